// Round 7
// baseline (219.106 us; speedup 1.0000x reference)
//
#include <hip/hip_runtime.h>
#include <hip/hip_bf16.h>

// Fused single-head attention, MI355X.
//   index [8,2048,1024] f32; Wq/Wk/Wv [1024,128] f32; out [8,2048,128] f32.
// wprep:    W -> Wt bf16 [n][k]  (Wq pre-scaled by 1/sqrt(1024) — exact in bf16)
// qkv_gemm: LDS-free direct-from-global GEMM with EXPLICIT 3-buffer register
//           software pipeline. R6 post-mortem: compiler does NOT software-
//           pipeline (VGPR=52 serial chain, 101µs, MfmaUtil 4.8%, and L3-warm
//           replays at 12.6MB HBM were STILL 100µs => pure latency stalls).
//           Loads for step s+2 are issued in source before MFMAs of step s.
// attn:     barrier-free flash (byte-identical to R3/R6 PASSING version).
// Workspace: qb 4MB | kb 4MB | vt 4MB | Wt 768KB  (ws_size >= 13.5MB)

typedef __attribute__((ext_vector_type(8))) short bf16x8;
typedef __attribute__((ext_vector_type(4))) float f32x4;
typedef __attribute__((ext_vector_type(4))) int i32x4;

#define TB 8
#define TT 2048
#define TC 1024
#define TH 128
#define LOG2E 1.4426950408889634f
#define NEGBIG (-1e30f)
#define RESCALE_THR 8.0f

__device__ __forceinline__ float fexp2(float x) {
#if __has_builtin(__builtin_amdgcn_exp2f)
  return __builtin_amdgcn_exp2f(x);
#else
  return exp2f(x);
#endif
}
__device__ __forceinline__ float eexp(float y) { return fexp2(y * LOG2E); }

__device__ __forceinline__ short bf16s(float a) {
  __hip_bfloat16 h = __float2bfloat16(a);
  return *reinterpret_cast<short*>(&h);
}
__device__ __forceinline__ unsigned pk2(float a, float b) {
  float2 t; t.x = a; t.y = b;
  __hip_bfloat162 h = __float22bfloat162_rn(t);
  return *reinterpret_cast<unsigned*>(&h);
}

// ---- Wt[w][n][k] bf16 <- W_w[k][n] f32 ; Wq scaled by 1/32 (exact: pow2)
__global__ void wprep(const float* __restrict__ wq, const float* __restrict__ wk,
                      const float* __restrict__ wv, short* __restrict__ wt) {
  int id = blockIdx.x * 256 + threadIdx.x;     // 0..393215
  int w = id >> 17;                            // /131072
  int r = id & 131071;
  int n = r >> 10, k = r & 1023;
  const float* src = (w == 0) ? wq : (w == 1) ? wk : wv;
  float v = src[k * TH + n];
  if (w == 0) v *= 0.03125f;                   // fold 1/sqrt(C) into q
  wt[id] = bf16s(v);
}

// ---- QKV projection: x[16384,1024] @ Wt -> q,k row-major bf16; v -> vt[b][h][t]
// BM=64, BN=128 per block; 4 waves = 2 row-halves x 2 col-halves; 32 K-steps
// of 32. 768 blocks = 3/CU. No LDS/barriers; manual 3-deep register pipeline.
// QLOAD(buf, s): issue step-s loads (raw f32 A + bf16 B) into named buffer.
// QUSE(buf): cvt A to bf16 and run the 8 MFMAs. Issue distance = 2 steps.
#define QLOAD(AL, AH, B, S) do {                                              \
    int ko_ = (S) * 32;                                                       \
    _Pragma("unroll")                                                         \
    for (int mf_ = 0; mf_ < 2; mf_++) {                                       \
      const float* p_ = arow + (size_t)mf_ * 16 * TC + ko_;                   \
      AL[mf_] = *reinterpret_cast<const float4*>(p_);                         \
      AH[mf_] = *reinterpret_cast<const float4*>(p_ + 4);                     \
    }                                                                         \
    _Pragma("unroll")                                                         \
    for (int nf_ = 0; nf_ < 4; nf_++)                                         \
      B[nf_] = *reinterpret_cast<const bf16x8*>(brow + (size_t)nf_ * 16 * TC + ko_); \
  } while (0)

#define QUSE(AL, AH, B) do {                                                  \
    bf16x8 a_[2];                                                             \
    _Pragma("unroll")                                                         \
    for (int mf_ = 0; mf_ < 2; mf_++) {                                       \
      union { bf16x8 v; unsigned u[4]; } pk_;                                 \
      pk_.u[0] = pk2(AL[mf_].x, AL[mf_].y); pk_.u[1] = pk2(AL[mf_].z, AL[mf_].w); \
      pk_.u[2] = pk2(AH[mf_].x, AH[mf_].y); pk_.u[3] = pk2(AH[mf_].z, AH[mf_].w); \
      a_[mf_] = pk_.v;                                                        \
    }                                                                         \
    _Pragma("unroll")                                                         \
    for (int mf_ = 0; mf_ < 2; mf_++)                                         \
      _Pragma("unroll")                                                       \
      for (int nf_ = 0; nf_ < 4; nf_++)                                       \
        acc[mf_][nf_] = __builtin_amdgcn_mfma_f32_16x16x32_bf16(              \
            a_[mf_], B[nf_], acc[mf_][nf_], 0, 0, 0);                         \
  } while (0)

__global__ __launch_bounds__(256, 3) void qkv_gemm(
    const float* __restrict__ x, const short* __restrict__ wt,
    short* __restrict__ qb, short* __restrict__ kb, short* __restrict__ vt) {
  int phys = blockIdx.x;
  int logical = (phys & 7) * 96 + (phys >> 3);   // 768 = 8 XCD * 96
  int rt = logical / 3, w = logical - rt * 3;    // row-tile (64 rows), w in {q,k,v}
  int row0 = rt << 6;
  const short* wsel = wt + w * (TH * TC);
  int tid = threadIdx.x;
  int lane = tid & 63;
  int wid = tid >> 6;
  int wr = wid >> 1, wc = wid & 1;               // wave -> (32-row, 64-col) quadrant
  int l15 = lane & 15, g = lane >> 4;

  f32x4 zero = {0.f, 0.f, 0.f, 0.f};
  f32x4 acc[2][4];
#pragma unroll
  for (int i = 0; i < 2; i++)
#pragma unroll
    for (int jj = 0; jj < 4; jj++) acc[i][jj] = zero;

  // lane's base pointers: A row = row0 + wr*32 + mf*16 + l15, k = step*32 + g*8
  //                       B row(n) = wc*64 + nf*16 + l15,     k = step*32 + g*8
  const float* arow = x + (size_t)(row0 + wr * 32 + l15) * TC + g * 8;
  const short* brow = wsel + (size_t)(wc * 64 + l15) * TC + g * 8;

  // 3 named pipeline buffers (static indices only — rule #20)
  float4 aL0[2], aH0[2]; bf16x8 b0[4];
  float4 aL1[2], aH1[2]; bf16x8 b1[4];
  float4 aL2[2], aH2[2]; bf16x8 b2[4];

  QLOAD(aL0, aH0, b0, 0);
  QLOAD(aL1, aH1, b1, 1);
  for (int i = 0; i < 10; i++) {                 // steps 0..29 used, 2..31 loaded
    QLOAD(aL2, aH2, b2, 3 * i + 2);  QUSE(aL0, aH0, b0);
    QLOAD(aL0, aH0, b0, 3 * i + 3);  QUSE(aL1, aH1, b1);
    QLOAD(aL1, aH1, b1, 3 * i + 4);  QUSE(aL2, aH2, b2);
  }
  QUSE(aL0, aH0, b0);                            // step 30
  QUSE(aL1, aH1, b1);                            // step 31

  // epilogue: C/D layout col=lane&15, row=(lane>>4)*4+reg  (HW-verified: R3/R6 passed)
#pragma unroll
  for (int mf = 0; mf < 2; mf++)
#pragma unroll
    for (int nf = 0; nf < 4; nf++)
#pragma unroll
      for (int r = 0; r < 4; r++) {
        int m = row0 + wr * 32 + mf * 16 + g * 4 + r;
        int n = wc * 64 + nf * 16 + l15;
        short hv = bf16s(acc[mf][nf][r]);
        if (w == 0) qb[(size_t)m * TH + n] = hv;
        else if (w == 1) kb[(size_t)m * TH + n] = hv;
        else {
          int bb = m >> 11, t = m & 2047;        // v stored transposed for PV B-frags
          vt[((size_t)bb * TH + n) * TT + t] = hv;
        }
      }
}

// ---- barrier-free flash attention (byte-identical to R3/R6 passing version).
// Grid 512. b = bid&7 (per-XCD batch pinning). qt mapped so bid c and c+256
// get (63-s, s): under round-robin placement each CU's two resident blocks
// sum to constant work. Wave wv privately owns kv chunks [j*128+wv*32, +32).
// acc[qf][hf]: q = qf*16+g*4+r, h = hf*16+l15.
__global__ __launch_bounds__(256, 2) void attn(
    const short* __restrict__ qb, const short* __restrict__ kb,
    const short* __restrict__ vt, float* __restrict__ out) {
  __shared__ float buf[4 * 32 * 128];            // 64KB partial-O tiles
  __shared__ float cm[4][32];
  __shared__ float cl[4][32];
  __shared__ float linv[32];
  int tid = threadIdx.x;
  int lane = tid & 63, wv = tid >> 6;
  int l15 = lane & 15, g = lane >> 4;
  int bid = blockIdx.x;
  int b = bid & 7;
  int s_ = bid >> 3;                             // 0..63
  int qt = (bid < 256) ? (63 - s_) : (s_ - 32);  // pair (63-s, s) per CU
  int q0 = qt << 5;

  // Q B-frags (hoisted): col q = q0+qf*16+l15, k = h = ks*32+g*8
  bf16x8 qfr[2][4];
  const short* qrow = qb + ((size_t)(b * TT + q0 + l15)) * TH + g * 8;
#pragma unroll
  for (int qf = 0; qf < 2; qf++)
#pragma unroll
    for (int ks = 0; ks < 4; ks++)
      qfr[qf][ks] = *reinterpret_cast<const bf16x8*>(qrow + (size_t)qf * 16 * TH + ks * 32);

  f32x4 zero = {0.f, 0.f, 0.f, 0.f};
  f32x4 acc[2][8];
#pragma unroll
  for (int qf = 0; qf < 2; qf++)
#pragma unroll
    for (int hf = 0; hf < 8; hf++) acc[qf][hf] = zero;
  float m_r[2] = {NEGBIG, NEGBIG};
  float l_r[2] = {0.f, 0.f};

  int lim = q0 + 31 - wv * 32;                   // kv0 mult of 32 & <= q0
  int nj = (lim >= 0) ? (lim >> 7) + 1 : 0;      //  => every q-row has >=1 live kv
  const short* kbase = kb + ((size_t)b * TT) * TH;
  const short* vbase = vt + ((size_t)b * TH) * TT;

  for (int j = 0; j < nj; j++) {
    int kv0 = j * 128 + wv * 32;
    // K A-frags: row kv = kv0+kvf*16+l15, k = h = ks*32+g*8  (L2-direct)
    bf16x8 kfr[2][4];
#pragma unroll
    for (int kvf = 0; kvf < 2; kvf++)
#pragma unroll
      for (int ks = 0; ks < 4; ks++)
        kfr[kvf][ks] = *reinterpret_cast<const bf16x8*>(
            kbase + (size_t)(kv0 + kvf * 16 + l15) * TH + ks * 32 + g * 8);
    // V B-frags: col h = hf*16+l15, k = kv = kv0+g*8+i  (vt is [h][t])
    bf16x8 vfr[8];
#pragma unroll
    for (int hf = 0; hf < 8; hf++)
      vfr[hf] = *reinterpret_cast<const bf16x8*>(
          vbase + (size_t)(hf * 16 + l15) * TT + kv0 + g * 8);

    // swapped QK^T: s[kvf][qf] = S^T[kv = kv0+kvf*16+g*4+r][q = q0+qf*16+l15]
    f32x4 s[2][2];
    s[0][0] = zero; s[0][1] = zero; s[1][0] = zero; s[1][1] = zero;
    __builtin_amdgcn_s_setprio(1);
#pragma unroll
    for (int ks = 0; ks < 4; ks++)
#pragma unroll
      for (int kvf = 0; kvf < 2; kvf++)
#pragma unroll
        for (int qf = 0; qf < 2; qf++)
          s[kvf][qf] = __builtin_amdgcn_mfma_f32_16x16x32_bf16(
              kfr[kvf][ks], qfr[qf][ks], s[kvf][qf], 0, 0, 0);
    __builtin_amdgcn_s_setprio(0);

    // causal mask + per-q row max (reduce over g: lanes ^16, ^32)
    float mm[2];
#pragma unroll
    for (int qf = 0; qf < 2; qf++) {
      int qg = q0 + qf * 16 + l15;
      float t = NEGBIG;
#pragma unroll
      for (int kvf = 0; kvf < 2; kvf++)
#pragma unroll
        for (int r = 0; r < 4; r++) {
          int kvg = kv0 + kvf * 16 + g * 4 + r;
          float v = s[kvf][qf][r];
          v = (kvg > qg) ? NEGBIG : v;
          s[kvf][qf][r] = v;
          t = fmaxf(t, v);
        }
      t = fmaxf(t, __shfl_xor(t, 16));
      t = fmaxf(t, __shfl_xor(t, 32));
      mm[qf] = t;
    }
    // defer-rescale (T13): skip O-rescale while max growth <= THR
    bool skip = __all((mm[0] - m_r[0] <= RESCALE_THR) &&
                      (mm[1] - m_r[1] <= RESCALE_THR));
    if (!skip) {
#pragma unroll
      for (int qf = 0; qf < 2; qf++) {
        float mn = fmaxf(m_r[qf], mm[qf]);
        float al = eexp(m_r[qf] - mn);
        m_r[qf] = mn;
        l_r[qf] *= al;
#pragma unroll
        for (int r = 0; r < 4; r++) {
          float av = __shfl(al, g * 4 + r);      // alpha for q_local = qf*16+g*4+r
#pragma unroll
          for (int hf = 0; hf < 8; hf++) acc[qf][hf][r] *= av;
        }
      }
    }
    // exp, l-update, repack P into K=32 A-frag (lane g needs kv g*8..g*8+7), PV
#pragma unroll
    for (int qf = 0; qf < 2; qf++) {
      float pv0 = eexp(s[0][qf][0] - m_r[qf]);
      float pv1 = eexp(s[0][qf][1] - m_r[qf]);
      float pv2 = eexp(s[0][qf][2] - m_r[qf]);
      float pv3 = eexp(s[0][qf][3] - m_r[qf]);
      float pw0 = eexp(s[1][qf][0] - m_r[qf]);
      float pw1 = eexp(s[1][qf][1] - m_r[qf]);
      float pw2 = eexp(s[1][qf][2] - m_r[qf]);
      float pw3 = eexp(s[1][qf][3] - m_r[qf]);
      float ps = ((pv0 + pv1) + (pv2 + pv3)) + ((pw0 + pw1) + (pw2 + pw3));
      ps += __shfl_xor(ps, 16);
      ps += __shfl_xor(ps, 32);
      l_r[qf] += ps;
      unsigned d0 = pk2(pv0, pv1), d1 = pk2(pv2, pv3);   // kvf=0: kv g'*4+{01,23}
      unsigned e0 = pk2(pw0, pw1), e1 = pk2(pw2, pw3);   // kvf=1: kv 16+g'*4+...
      // target lane (l15,g) needs kv pairs {g*8+01, g*8+23, g*8+45, g*8+67}:
      //   g=0: d@g'0,d@g'1  g=1: d@g'2,d@g'3  g=2: e@g'0,e@g'1  g=3: e@g'2,e@g'3
      int lA_ = l15 + ((g & 1) << 5);
      int lB_ = lA_ + 16;
      int xa0 = __shfl((int)d0, lA_), xe0 = __shfl((int)e0, lA_);
      int xa1 = __shfl((int)d1, lA_), xe1 = __shfl((int)e1, lA_);
      int ya0 = __shfl((int)d0, lB_), ye0 = __shfl((int)e0, lB_);
      int ya1 = __shfl((int)d1, lB_), ye1 = __shfl((int)e1, lB_);
      bool hi = (g >= 2);
      i32x4 fr;
      fr.x = hi ? xe0 : xa0;
      fr.y = hi ? xe1 : xa1;
      fr.z = hi ? ye0 : ya0;
      fr.w = hi ? ye1 : ya1;
      bf16x8 pa = *reinterpret_cast<bf16x8*>(&fr);
      __builtin_amdgcn_s_setprio(1);
#pragma unroll
      for (int hf = 0; hf < 8; hf++)
        acc[qf][hf] = __builtin_amdgcn_mfma_f32_16x16x32_bf16(pa, vfr[hf], acc[qf][hf], 0, 0, 0);
      __builtin_amdgcn_s_setprio(0);
    }
  }

  // ---- cross-wave combine (2 barriers per block) ----
  if (g == 0) {
    cm[wv][l15] = m_r[0]; cm[wv][16 + l15] = m_r[1];
    cl[wv][l15] = l_r[0]; cl[wv][16 + l15] = l_r[1];
  }
  __syncthreads();
  float wgt[2];
#pragma unroll
  for (int qf = 0; qf < 2; qf++) {
    int ql = qf * 16 + l15;
    float M = fmaxf(fmaxf(cm[0][ql], cm[1][ql]), fmaxf(cm[2][ql], cm[3][ql]));
    wgt[qf] = eexp(m_r[qf] - M);
    if (wv == 0 && g == 0) {
      float lt = 0.f;
#pragma unroll
      for (int t = 0; t < 4; t++)
        lt += eexp(cm[t][ql] - M) * cl[t][ql];
      linv[ql] = 1.0f / lt;
    }
  }
#pragma unroll
  for (int qf = 0; qf < 2; qf++)
#pragma unroll
    for (int r = 0; r < 4; r++) {
      float w_ = __shfl(wgt[qf], g * 4 + r);
      int row = qf * 16 + g * 4 + r;
#pragma unroll
      for (int hf = 0; hf < 8; hf++)
        buf[(wv * 32 + row) * 128 + hf * 16 + l15] = acc[qf][hf][r] * w_;
    }
  __syncthreads();
  // strip-sum: wave wv sums q rows [wv*8, wv*8+8) over the 4 partials
#pragma unroll
  for (int rep = 0; rep < 4; rep++) {
    int row = wv * 8 + rep * 2 + (lane >> 5);
    int col = (lane & 31) * 4;
    f32x4 sum = *reinterpret_cast<f32x4*>(&buf[row * 128 + col]);
#pragma unroll
    for (int t = 1; t < 4; t++)
      sum += *reinterpret_cast<f32x4*>(&buf[(t * 32 + row) * 128 + col]);
    float li = linv[row];
    f32x4 o = sum * li;
    *reinterpret_cast<f32x4*>(&out[((size_t)(b * TT + q0 + row)) * TH + col]) = o;
  }
}

extern "C" void kernel_launch(void* const* d_in, const int* in_sizes, int n_in,
                              void* d_out, int out_size, void* d_ws, size_t ws_size,
                              hipStream_t stream) {
  const float* x  = (const float*)d_in[0];
  const float* wq = (const float*)d_in[1];
  const float* wk = (const float*)d_in[2];
  const float* wv = (const float*)d_in[3];
  float* out = (float*)d_out;
  char* ws = (char*)d_ws;
  short* qb = (short*)(ws);                       // 4MB  q bf16 [16384][128] (pre-scaled)
  short* kb = (short*)(ws + (size_t)(4u << 20));  // 4MB  k bf16 [16384][128]
  short* vt = (short*)(ws + (size_t)(8u << 20));  // 4MB  v bf16 transposed [8][128][2048]
  short* wt = (short*)(ws + (size_t)(12u << 20)); // 768KB Wt bf16 [3][128][1024]

  wprep<<<1536, 256, 0, stream>>>(wq, wk, wv, wt);
  qkv_gemm<<<768, 256, 0, stream>>>(x, wt, qb, kb, vt);
  attn<<<512, 256, 0, stream>>>(qb, kb, vt, out);
}

// Round 9
// 163.936 us; speedup vs baseline: 1.3365x; 1.3365x over previous
//
#include <hip/hip_runtime.h>
#include <hip/hip_bf16.h>

// Fused single-head attention, MI355X.
//   index [8,2048,1024] f32; Wq/Wk/Wv [1024,128] f32; out [8,2048,128] f32.
// wprep:    W -> Wt bf16 [n][k] via LDS transpose (coalesced both sides);
//           Wq pre-scaled by 1/sqrt(1024) (exact in bf16).
// qkv_gemm: m97-style 2-barrier LDS loop, global_load_lds(16B) staging for
//           BOTH operands (A kept f32 in LDS, cvt at read). XOR-swizzled
//           source + XOR-swizzled ds_read (rule #21 both-sides). R6/R7
//           post-mortem: compiler re-serializes ANY register-staged global
//           load chain (VGPR 52/68, MfmaUtil <5%); global_load_lds is the
//           one staging path it cannot sink.
// attn:     barrier-free flash (byte-identical to 3x-passing version).
// Workspace: qb 4MB | kb 4MB | vt 4MB | Wt 768KB  (ws_size >= 13.5MB)

typedef __attribute__((ext_vector_type(8))) short bf16x8;
typedef __attribute__((ext_vector_type(4))) float f32x4;
typedef __attribute__((ext_vector_type(4))) int i32x4;

#define TB 8
#define TT 2048
#define TC 1024
#define TH 128
#define LOG2E 1.4426950408889634f
#define NEGBIG (-1e30f)
#define RESCALE_THR 8.0f

__device__ __forceinline__ float fexp2(float x) {
#if __has_builtin(__builtin_amdgcn_exp2f)
  return __builtin_amdgcn_exp2f(x);
#else
  return exp2f(x);
#endif
}
__device__ __forceinline__ float eexp(float y) { return fexp2(y * LOG2E); }

__device__ __forceinline__ short bf16s(float a) {
  __hip_bfloat16 h = __float2bfloat16(a);
  return *reinterpret_cast<short*>(&h);
}
__device__ __forceinline__ unsigned pk2(float a, float b) {
  float2 t; t.x = a; t.y = b;
  __hip_bfloat162 h = __float22bfloat162_rn(t);
  return *reinterpret_cast<unsigned*>(&h);
}
__device__ __forceinline__ void gload16(const void* g, void* l) {
  __builtin_amdgcn_global_load_lds(
      (const __attribute__((address_space(1))) void*)g,
      (__attribute__((address_space(3))) void*)l, 16, 0, 0);
}

// ---- Wt[w][n][k] bf16 <- W_w[k][n] f32, LDS-transposed; Wq scaled by 1/32.
// Grid 48 = 3 w * 16 k-tiles(64). Reads coalesced on n, writes coalesced on k.
__global__ void wprep(const float* __restrict__ wq, const float* __restrict__ wk,
                      const float* __restrict__ wv, short* __restrict__ wt) {
  __shared__ float t[64 * 129];                  // +1 pad kills transpose conflicts
  int tid = threadIdx.x;
  int blk = blockIdx.x;
  int w = blk >> 4, kt = blk & 15;
  int k0 = kt << 6;
  const float* src = (w == 0) ? wq : (w == 1) ? wk : wv;
  float scale = (w == 0) ? 0.03125f : 1.0f;
#pragma unroll
  for (int i = 0; i < 32; i++) {
    int lin = i * 256 + tid;                     // 0..8191
    int kl = lin >> 7, n = lin & 127;
    t[kl * 129 + n] = src[(size_t)(k0 + kl) * TH + n];
  }
  __syncthreads();
#pragma unroll
  for (int i = 0; i < 32; i++) {
    int lin = i * 256 + tid;
    int n = lin >> 6, kl = lin & 63;
    wt[(size_t)w * (TH * TC) + (size_t)n * TC + k0 + kl] = bf16s(t[kl * 129 + n] * scale);
  }
}

// ---- QKV projection: x[16384,1024] @ Wt -> q,k row-major bf16; v -> vt[b][h][t]
// BM=64, BN=128, BK=64; 4 waves (2m x 2n); 768 blocks = 3/CU.
// LDS: A f32 [64 rows][16 chunks of 16B], slot(r,c) = r*16 + (c ^ (r&15));
//      B bf16 [128 rows][8 chunks of 16B], slot(r,c) = r*8  + (c ^ (r&7)).
// Staged by global_load_lds(16B) with inverse-swizzled global source.
__global__ __launch_bounds__(256, 3) void qkv_gemm(
    const float* __restrict__ x, const short* __restrict__ wt,
    short* __restrict__ qb, short* __restrict__ kb, short* __restrict__ vt) {
  __shared__ __align__(16) float lA[4096];       // 16KB
  __shared__ __align__(16) short lB[8192];       // 16KB
  int phys = blockIdx.x;
  int logical = (phys & 7) * 96 + (phys >> 3);   // 768 = 8 XCD * 96
  int rt = logical / 3, w = logical - rt * 3;    // row-tile (64 rows), w in {q,k,v}
  int row0 = rt << 6;
  const short* wsel = wt + w * (TH * TC);
  int tid = threadIdx.x;
  int lane = tid & 63;
  int wid = tid >> 6;
  int wr = wid >> 1, wc = wid & 1;               // wave -> (32-row, 64-col) quadrant
  int l15 = lane & 15, g = lane >> 4;

  f32x4 zero = {0.f, 0.f, 0.f, 0.f};
  f32x4 acc[2][4];
#pragma unroll
  for (int i = 0; i < 2; i++)
#pragma unroll
    for (int jj = 0; jj < 4; jj++) acc[i][jj] = zero;

  for (int k0 = 0; k0 < TC; k0 += 64) {
    __syncthreads();                             // prev iter's LDS reads done
    // stage A: 1024 slots of 16B; thread covers slot it*256+tid
#pragma unroll
    for (int it = 0; it < 4; it++) {
      int s = it * 256 + tid;
      int r = s >> 4, cphys = s & 15;
      int clog = cphys ^ (r & 15);               // involution: src for this slot
      const float* gp = x + (size_t)(row0 + r) * TC + k0 + (clog << 2);
      gload16(gp, &lA[(size_t)(it * 256 + wid * 64) * 4]);  // wave-uniform base
    }
    // stage B: 1024 slots of 16B
#pragma unroll
    for (int it = 0; it < 4; it++) {
      int s = it * 256 + tid;
      int r = s >> 3, cphys = s & 7;
      int clog = cphys ^ (r & 7);
      const short* gp = wsel + (size_t)r * TC + k0 + (clog << 3);
      gload16(gp, &lB[(size_t)(it * 256 + wid * 64) * 8]);
    }
    __syncthreads();                             // implicit vmcnt(0): staging landed
#pragma unroll
    for (int ks = 0; ks < 2; ks++) {
      bf16x8 a[2], b[4];
#pragma unroll
      for (int mf = 0; mf < 2; mf++) {
        int r = wr * 32 + mf * 16 + l15;
        int c0 = ks * 8 + g * 2;                 // even logical chunk
        int p0 = c0 ^ (r & 15);
        f32x4 alo = *reinterpret_cast<const f32x4*>(&lA[(r * 16 + p0) * 4]);
        f32x4 ahi = *reinterpret_cast<const f32x4*>(&lA[(r * 16 + (p0 ^ 1)) * 4]);
        union { bf16x8 v; unsigned u[4]; } pk_;
        pk_.u[0] = pk2(alo[0], alo[1]); pk_.u[1] = pk2(alo[2], alo[3]);
        pk_.u[2] = pk2(ahi[0], ahi[1]); pk_.u[3] = pk2(ahi[2], ahi[3]);
        a[mf] = pk_.v;
      }
#pragma unroll
      for (int nf = 0; nf < 4; nf++) {
        int rn = wc * 64 + nf * 16 + l15;
        int c = ks * 4 + g;
        int p = c ^ (rn & 7);
        b[nf] = *reinterpret_cast<const bf16x8*>(&lB[(rn * 8 + p) * 8]);
      }
#pragma unroll
      for (int mf = 0; mf < 2; mf++)
#pragma unroll
        for (int nf = 0; nf < 4; nf++)
          acc[mf][nf] = __builtin_amdgcn_mfma_f32_16x16x32_bf16(a[mf], b[nf], acc[mf][nf], 0, 0, 0);
    }
  }
  // epilogue: C/D layout col=lane&15, row=(lane>>4)*4+reg  (HW-verified 3x)
#pragma unroll
  for (int mf = 0; mf < 2; mf++)
#pragma unroll
    for (int nf = 0; nf < 4; nf++)
#pragma unroll
      for (int r = 0; r < 4; r++) {
        int m = row0 + wr * 32 + mf * 16 + g * 4 + r;
        int n = wc * 64 + nf * 16 + l15;
        short hv = bf16s(acc[mf][nf][r]);
        if (w == 0) qb[(size_t)m * TH + n] = hv;
        else if (w == 1) kb[(size_t)m * TH + n] = hv;
        else {
          int bb = m >> 11, t = m & 2047;        // v stored transposed for PV B-frags
          vt[((size_t)bb * TH + n) * TT + t] = hv;
        }
      }
}

// ---- barrier-free flash attention (byte-identical to 3x-passing version).
// Grid 512. b = bid&7 (per-XCD batch pinning). qt mapped so bid c and c+256
// get (63-s, s): under round-robin placement each CU's two resident blocks
// sum to constant work. Wave wv privately owns kv chunks [j*128+wv*32, +32).
// acc[qf][hf]: q = qf*16+g*4+r, h = hf*16+l15.
__global__ __launch_bounds__(256, 2) void attn(
    const short* __restrict__ qb, const short* __restrict__ kb,
    const short* __restrict__ vt, float* __restrict__ out) {
  __shared__ float buf[4 * 32 * 128];            // 64KB partial-O tiles
  __shared__ float cm[4][32];
  __shared__ float cl[4][32];
  __shared__ float linv[32];
  int tid = threadIdx.x;
  int lane = tid & 63, wv = tid >> 6;
  int l15 = lane & 15, g = lane >> 4;
  int bid = blockIdx.x;
  int b = bid & 7;
  int s_ = bid >> 3;                             // 0..63
  int qt = (bid < 256) ? (63 - s_) : (s_ - 32);  // pair (63-s, s) per CU
  int q0 = qt << 5;

  // Q B-frags (hoisted): col q = q0+qf*16+l15, k = h = ks*32+g*8
  bf16x8 qfr[2][4];
  const short* qrow = qb + ((size_t)(b * TT + q0 + l15)) * TH + g * 8;
#pragma unroll
  for (int qf = 0; qf < 2; qf++)
#pragma unroll
    for (int ks = 0; ks < 4; ks++)
      qfr[qf][ks] = *reinterpret_cast<const bf16x8*>(qrow + (size_t)qf * 16 * TH + ks * 32);

  f32x4 zero = {0.f, 0.f, 0.f, 0.f};
  f32x4 acc[2][8];
#pragma unroll
  for (int qf = 0; qf < 2; qf++)
#pragma unroll
    for (int hf = 0; hf < 8; hf++) acc[qf][hf] = zero;
  float m_r[2] = {NEGBIG, NEGBIG};
  float l_r[2] = {0.f, 0.f};

  int lim = q0 + 31 - wv * 32;                   // kv0 mult of 32 & <= q0
  int nj = (lim >= 0) ? (lim >> 7) + 1 : 0;      //  => every q-row has >=1 live kv
  const short* kbase = kb + ((size_t)b * TT) * TH;
  const short* vbase = vt + ((size_t)b * TH) * TT;

  for (int j = 0; j < nj; j++) {
    int kv0 = j * 128 + wv * 32;
    // K A-frags: row kv = kv0+kvf*16+l15, k = h = ks*32+g*8  (L2-direct)
    bf16x8 kfr[2][4];
#pragma unroll
    for (int kvf = 0; kvf < 2; kvf++)
#pragma unroll
      for (int ks = 0; ks < 4; ks++)
        kfr[kvf][ks] = *reinterpret_cast<const bf16x8*>(
            kbase + (size_t)(kv0 + kvf * 16 + l15) * TH + ks * 32 + g * 8);
    // V B-frags: col h = hf*16+l15, k = kv = kv0+g*8+i  (vt is [h][t])
    bf16x8 vfr[8];
#pragma unroll
    for (int hf = 0; hf < 8; hf++)
      vfr[hf] = *reinterpret_cast<const bf16x8*>(
          vbase + (size_t)(hf * 16 + l15) * TT + kv0 + g * 8);

    // swapped QK^T: s[kvf][qf] = S^T[kv = kv0+kvf*16+g*4+r][q = q0+qf*16+l15]
    f32x4 s[2][2];
    s[0][0] = zero; s[0][1] = zero; s[1][0] = zero; s[1][1] = zero;
    __builtin_amdgcn_s_setprio(1);
#pragma unroll
    for (int ks = 0; ks < 4; ks++)
#pragma unroll
      for (int kvf = 0; kvf < 2; kvf++)
#pragma unroll
        for (int qf = 0; qf < 2; qf++)
          s[kvf][qf] = __builtin_amdgcn_mfma_f32_16x16x32_bf16(
              kfr[kvf][ks], qfr[qf][ks], s[kvf][qf], 0, 0, 0);
    __builtin_amdgcn_s_setprio(0);

    // causal mask + per-q row max (reduce over g: lanes ^16, ^32)
    float mm[2];
#pragma unroll
    for (int qf = 0; qf < 2; qf++) {
      int qg = q0 + qf * 16 + l15;
      float t = NEGBIG;
#pragma unroll
      for (int kvf = 0; kvf < 2; kvf++)
#pragma unroll
        for (int r = 0; r < 4; r++) {
          int kvg = kv0 + kvf * 16 + g * 4 + r;
          float v = s[kvf][qf][r];
          v = (kvg > qg) ? NEGBIG : v;
          s[kvf][qf][r] = v;
          t = fmaxf(t, v);
        }
      t = fmaxf(t, __shfl_xor(t, 16));
      t = fmaxf(t, __shfl_xor(t, 32));
      mm[qf] = t;
    }
    // defer-rescale (T13): skip O-rescale while max growth <= THR
    bool skip = __all((mm[0] - m_r[0] <= RESCALE_THR) &&
                      (mm[1] - m_r[1] <= RESCALE_THR));
    if (!skip) {
#pragma unroll
      for (int qf = 0; qf < 2; qf++) {
        float mn = fmaxf(m_r[qf], mm[qf]);
        float al = eexp(m_r[qf] - mn);
        m_r[qf] = mn;
        l_r[qf] *= al;
#pragma unroll
        for (int r = 0; r < 4; r++) {
          float av = __shfl(al, g * 4 + r);      // alpha for q_local = qf*16+g*4+r
#pragma unroll
          for (int hf = 0; hf < 8; hf++) acc[qf][hf][r] *= av;
        }
      }
    }
    // exp, l-update, repack P into K=32 A-frag (lane g needs kv g*8..g*8+7), PV
#pragma unroll
    for (int qf = 0; qf < 2; qf++) {
      float pv0 = eexp(s[0][qf][0] - m_r[qf]);
      float pv1 = eexp(s[0][qf][1] - m_r[qf]);
      float pv2 = eexp(s[0][qf][2] - m_r[qf]);
      float pv3 = eexp(s[0][qf][3] - m_r[qf]);
      float pw0 = eexp(s[1][qf][0] - m_r[qf]);
      float pw1 = eexp(s[1][qf][1] - m_r[qf]);
      float pw2 = eexp(s[1][qf][2] - m_r[qf]);
      float pw3 = eexp(s[1][qf][3] - m_r[qf]);
      float ps = ((pv0 + pv1) + (pv2 + pv3)) + ((pw0 + pw1) + (pw2 + pw3));
      ps += __shfl_xor(ps, 16);
      ps += __shfl_xor(ps, 32);
      l_r[qf] += ps;
      unsigned d0 = pk2(pv0, pv1), d1 = pk2(pv2, pv3);   // kvf=0: kv g'*4+{01,23}
      unsigned e0 = pk2(pw0, pw1), e1 = pk2(pw2, pw3);   // kvf=1: kv 16+g'*4+...
      // target lane (l15,g) needs kv pairs {g*8+01, g*8+23, g*8+45, g*8+67}:
      //   g=0: d@g'0,d@g'1  g=1: d@g'2,d@g'3  g=2: e@g'0,e@g'1  g=3: e@g'2,e@g'3
      int lA_ = l15 + ((g & 1) << 5);
      int lB_ = lA_ + 16;
      int xa0 = __shfl((int)d0, lA_), xe0 = __shfl((int)e0, lA_);
      int xa1 = __shfl((int)d1, lA_), xe1 = __shfl((int)e1, lA_);
      int ya0 = __shfl((int)d0, lB_), ye0 = __shfl((int)e0, lB_);
      int ya1 = __shfl((int)d1, lB_), ye1 = __shfl((int)e1, lB_);
      bool hi = (g >= 2);
      i32x4 fr;
      fr.x = hi ? xe0 : xa0;
      fr.y = hi ? xe1 : xa1;
      fr.z = hi ? ye0 : ya0;
      fr.w = hi ? ye1 : ya1;
      bf16x8 pa = *reinterpret_cast<bf16x8*>(&fr);
      __builtin_amdgcn_s_setprio(1);
#pragma unroll
      for (int hf = 0; hf < 8; hf++)
        acc[qf][hf] = __builtin_amdgcn_mfma_f32_16x16x32_bf16(pa, vfr[hf], acc[qf][hf], 0, 0, 0);
      __builtin_amdgcn_s_setprio(0);
    }
  }

  // ---- cross-wave combine (2 barriers per block) ----
  if (g == 0) {
    cm[wv][l15] = m_r[0]; cm[wv][16 + l15] = m_r[1];
    cl[wv][l15] = l_r[0]; cl[wv][16 + l15] = l_r[1];
  }
  __syncthreads();
  float wgt[2];
#pragma unroll
  for (int qf = 0; qf < 2; qf++) {
    int ql = qf * 16 + l15;
    float M = fmaxf(fmaxf(cm[0][ql], cm[1][ql]), fmaxf(cm[2][ql], cm[3][ql]));
    wgt[qf] = eexp(m_r[qf] - M);
    if (wv == 0 && g == 0) {
      float lt = 0.f;
#pragma unroll
      for (int t = 0; t < 4; t++)
        lt += eexp(cm[t][ql] - M) * cl[t][ql];
      linv[ql] = 1.0f / lt;
    }
  }
#pragma unroll
  for (int qf = 0; qf < 2; qf++)
#pragma unroll
    for (int r = 0; r < 4; r++) {
      float w_ = __shfl(wgt[qf], g * 4 + r);
      int row = qf * 16 + g * 4 + r;
#pragma unroll
      for (int hf = 0; hf < 8; hf++)
        buf[(wv * 32 + row) * 128 + hf * 16 + l15] = acc[qf][hf][r] * w_;
    }
  __syncthreads();
  // strip-sum: wave wv sums q rows [wv*8, wv*8+8) over the 4 partials
#pragma unroll
  for (int rep = 0; rep < 4; rep++) {
    int row = wv * 8 + rep * 2 + (lane >> 5);
    int col = (lane & 31) * 4;
    f32x4 sum = *reinterpret_cast<f32x4*>(&buf[row * 128 + col]);
#pragma unroll
    for (int t = 1; t < 4; t++)
      sum += *reinterpret_cast<f32x4*>(&buf[(t * 32 + row) * 128 + col]);
    float li = linv[row];
    f32x4 o = sum * li;
    *reinterpret_cast<f32x4*>(&out[((size_t)(b * TT + q0 + row)) * TH + col]) = o;
  }
}

extern "C" void kernel_launch(void* const* d_in, const int* in_sizes, int n_in,
                              void* d_out, int out_size, void* d_ws, size_t ws_size,
                              hipStream_t stream) {
  const float* x  = (const float*)d_in[0];
  const float* wq = (const float*)d_in[1];
  const float* wk = (const float*)d_in[2];
  const float* wv = (const float*)d_in[3];
  float* out = (float*)d_out;
  char* ws = (char*)d_ws;
  short* qb = (short*)(ws);                       // 4MB  q bf16 [16384][128] (pre-scaled)
  short* kb = (short*)(ws + (size_t)(4u << 20));  // 4MB  k bf16 [16384][128]
  short* vt = (short*)(ws + (size_t)(8u << 20));  // 4MB  v bf16 transposed [8][128][2048]
  short* wt = (short*)(ws + (size_t)(12u << 20)); // 768KB Wt bf16 [3][128][1024]

  wprep<<<48, 256, 0, stream>>>(wq, wk, wv, wt);
  qkv_gemm<<<768, 256, 0, stream>>>(x, wt, qb, kb, vt);
  attn<<<512, 256, 0, stream>>>(qb, kb, vt, out);
}